// Round 5
// baseline (68.611 us; speedup 1.0000x reference)
//
#include <hip/hip_runtime.h>
#include <hip/hip_bf16.h>

typedef __attribute__((ext_vector_type(8))) short short8;
typedef __attribute__((ext_vector_type(8))) unsigned short u16x8;
typedef __attribute__((ext_vector_type(4))) float f32x4;

constexpr int NB = 64;     // batch
constexpr int NL = 96;     // time / conv channels
constexpr int NC = 2048;   // feature / conv spatial
constexpr int TT = 64;     // conv spatial tile per block
constexpr int KTOT = 288;  // conv GEMM K = 96 ch * 3 taps, k = tau*96 + i
constexpr int LROW = 104;  // LDS row pitch (bf16 elems), rows 16B-aligned
constexpr int XROWS = 80;  // staged x cols: 64 tile + 2 halo + 14 pad (5 n-tiles of 16)
constexpr float LOG2E = 1.44269504088896340736f;

__device__ inline unsigned short f2bf(float f) {
    union { float f; unsigned u; } v; v.f = f;
    unsigned r = v.u + 0x7fff + ((v.u >> 16) & 1);   // RNE
    return (unsigned short)(r >> 16);
}

// packed f32x2 -> bf16x2 (RNE); src0 -> low 16
__device__ inline unsigned cvt_pk_bf16(float lo, float hi) {
    unsigned r;
    asm("v_cvt_pk_bf16_f32 %0, %1, %2" : "=v"(r) : "v"(lo), "v"(hi));
    return r;
}
__device__ inline float fexp2(float x) {   // 2^x, single v_exp_f32
    float r; asm("v_exp_f32 %0, %1" : "=v"(r) : "v"(x)); return r;
}
__device__ inline float frcp(float x) {    // 1/x approx (~1 ulp)
    float r; asm("v_rcp_f32 %0, %1" : "=v"(r) : "v"(x)); return r;
}
__device__ inline float bflo(unsigned d) { return __uint_as_float(d << 16); }
__device__ inline float bfhi(unsigned d) { return __uint_as_float(d & 0xffff0000u); }

// ---------------------------------------------------------------------------
// Prep: (a) conv weights Aw[o][k], k = tau*96 + i, bf16;
//       (b) Mstack[3][96][96]: banded moving-average matrices with
//           replicate-pad mass folded into columns j=0 / j=95, scaled 1/K.
// ---------------------------------------------------------------------------
__global__ void prep_kernel(const float* __restrict__ w,
                            unsigned short* __restrict__ aw,
                            unsigned short* __restrict__ mstack)
{
    int idx = blockIdx.x * 256 + threadIdx.x;
    if (idx < NL * KTOT) {
        int o = idx / KTOT, k = idx - o * KTOT;
        int tau = k / NL, i = k - tau * NL;
        aw[idx] = f2bf(w[(o * NL + i) * 3 + tau]);
    } else if (idx < NL * KTOT + 3 * 96 * 96) {
        int r = idx - NL * KTOT;
        int kk = r / (96 * 96);
        int rem = r - kk * 96 * 96;
        int l0 = rem / 96, j = rem - l0 * 96;
        int p = (kk == 0) ? 2 : (kk == 1) ? 6 : 12;
        float cnt = (j >= l0 - p && j <= l0 + p) ? 1.0f : 0.0f;
        if (j == 0 && l0 < p)       cnt += (float)(p - l0);
        if (j == 95 && l0 + p > 95) cnt += (float)(l0 + p - 95);
        mstack[r] = f2bf(cnt / (float)(2 * p + 1));
    }
}

// ---------------------------------------------------------------------------
// Fused kernel, block = (batch b, 64-wide spatial tile):
//  Phase 0: stage x (80 cols x 96 l) bf16 -> LDS sx (GEMM-B layout [t][l]).
//  Phase 1: means via MFMA (Mstack @ x-tile, 30 trio-tiles; a trio = the
//           3 kernel rows for one (l-tile, n-tile), so each lane holds
//           m5/m13/m25 for the same (l,t) in 3 accumulators) ->
//           lane-local softmax gate -> mm bf16 -> LDS sm.
//  Phase 2: conv is linear: out1 = C(mm), out0 = C(x) - C(mm), one bf16
//           MFMA GEMM over B-tiles sx and sm (proven R2/R3 mapping).
// ---------------------------------------------------------------------------
__global__ __launch_bounds__(256, 4) void fused_kernel(
    const float* __restrict__ x,
    const float* __restrict__ gw,
    const float* __restrict__ gb,
    const unsigned short* __restrict__ aw,
    const unsigned short* __restrict__ mstack,
    float* __restrict__ out0,
    float* __restrict__ out1)
{
    __shared__ unsigned short sx[XROWS][LROW];    // x  tile, rows = local t
    __shared__ unsigned short sm[TT + 2][LROW];   // mm tile, rows = local t

    int b = blockIdx.x;
    int t0 = blockIdx.y * TT;
    size_t xb = (size_t)b * NL * NC;

    int lane = threadIdx.x & 63;
    int wv = threadIdx.x >> 6;
    int lr = lane & 15, lk = lane >> 4;

    // ---- Phase 0: stage x -> bf16 LDS (coalesced f32 loads, cvt_pk pairs)
    for (int u = threadIdx.x; u < XROWS * 12; u += 256) {
        int o = u / XROWS, c = u - o * XROWS;
        int t = (t0 - 1 + c) & (NC - 1);               // circular halo
        const float* xp = x + xb + (size_t)(o * 8) * NC + t;
        union { u16x8 v; unsigned d[4]; } pk;
#pragma unroll
        for (int h = 0; h < 4; ++h)
            pk.d[h] = cvt_pk_bf16(xp[(size_t)(2 * h) * NC], xp[(size_t)(2 * h + 1) * NC]);
        *(u16x8*)(&sx[c][o * 8]) = pk.v;
    }
    __syncthreads();

    // ---- Phase 1: MFMA means + lane-local softmax combine
    {
        float w0 = gw[0] * LOG2E, w1 = gw[1] * LOG2E, w2 = gw[2] * LOG2E;
        float b0 = gb[0] * LOG2E, b1 = gb[1] * LOG2E, b2 = gb[2] * LOG2E;

        for (int tr = wv; tr < 30; tr += 4) {
            int ntile = tr / 6, lt = tr - ntile * 6;   // n-tile 0..4, l-tile 0..5
            // A fragments: Mstack row = kk*96 + (lt*16 + lr), col-chunk lk*8
            const unsigned short* mrow = mstack + (size_t)(lt * 16 + lr) * 96 + lk * 8;
            short8 aM[3][3];
#pragma unroll
            for (int k = 0; k < 3; ++k)
#pragma unroll
                for (int kk = 0; kk < 3; ++kk)
                    aM[k][kk] = *(const short8*)(mrow + k * 96 * 96 + kk * 32);
            // B fragments: sx row = ntile*16 + lr (local t), col-chunk = K
            short8 bM[3];
#pragma unroll
            for (int kk = 0; kk < 3; ++kk)
                bM[kk] = *(const short8*)(&sx[ntile * 16 + lr][kk * 32 + lk * 8]);

            f32x4 ac[3] = {};
#pragma unroll
            for (int kk = 0; kk < 3; ++kk)
#pragma unroll
                for (int k = 0; k < 3; ++k)
                    ac[k] = __builtin_amdgcn_mfma_f32_16x16x32_bf16(
                        aM[k][kk], bM[kk], ac[k], 0, 0, 0);

            // combine: lane owns (l = lt*16 + lk*4 + r4, c = ntile*16 + lr)
            int c = ntile * 16 + lr;
            int lb = lt * 16 + lk * 4;
            unsigned d0 = *(const unsigned*)(&sx[c][lb]);
            unsigned d1 = *(const unsigned*)(&sx[c][lb + 2]);
            float mmv[4];
#pragma unroll
            for (int r4 = 0; r4 < 4; ++r4) {
                float xl = (r4 == 0) ? bflo(d0) : (r4 == 1) ? bfhi(d0)
                         : (r4 == 2) ? bflo(d1) : bfhi(d1);
                float e0 = fexp2(fmaf(xl, w0, b0));
                float e1 = fexp2(fmaf(xl, w1, b1));
                float e2 = fexp2(fmaf(xl, w2, b2));
                float inv = frcp(e0 + e1 + e2);
                mmv[r4] = fmaf(ac[0][r4], e0, fmaf(ac[1][r4], e1, ac[2][r4] * e2)) * inv;
            }
            if (c < TT + 2) {
                *(unsigned*)(&sm[c][lb])     = cvt_pk_bf16(mmv[0], mmv[1]);
                *(unsigned*)(&sm[c][lb + 2]) = cvt_pk_bf16(mmv[2], mmv[3]);
            }
        }
    }

    // main-GEMM A prefetch (L2-hot), issued before the barrier
    int mg = wv & 1, ng = wv >> 1;
    const unsigned short* abase = aw + (size_t)(mg * 48 + lr) * KTOT + lk * 8;
    short8 aCur[3], aNxt[3];
#pragma unroll
    for (int mt = 0; mt < 3; ++mt)
        aCur[mt] = *(const short8*)(abase + mt * 16 * KTOT);

    __syncthreads();

    // ---- Phase 2: conv GEMM over B-tiles {sx, sm}
    f32x4 acc[3][2][2] = {};

#pragma unroll
    for (int ks = 0; ks < 9; ++ks) {
        if (ks < 8) {
#pragma unroll
            for (int mt = 0; mt < 3; ++mt)
                aNxt[mt] = *(const short8*)(abase + mt * 16 * KTOT + (ks + 1) * 32);
        }
        const int tau = ks / 3;
        const int i0 = (ks - tau * 3) * 32;
        short8 bfx[2], bfm[2];
#pragma unroll
        for (int nt = 0; nt < 2; ++nt) {
            int r = ng * 32 + nt * 16 + lr + tau;   // LDS row = local t + tau (<= 65)
            bfx[nt] = *(const short8*)(&sx[r][i0 + lk * 8]);
            bfm[nt] = *(const short8*)(&sm[r][i0 + lk * 8]);
        }
#pragma unroll
        for (int mt = 0; mt < 3; ++mt)
#pragma unroll
            for (int nt = 0; nt < 2; ++nt) {
                acc[mt][nt][0] = __builtin_amdgcn_mfma_f32_16x16x32_bf16(
                    aCur[mt], bfx[nt], acc[mt][nt][0], 0, 0, 0);
                acc[mt][nt][1] = __builtin_amdgcn_mfma_f32_16x16x32_bf16(
                    aCur[mt], bfm[nt], acc[mt][nt][1], 0, 0, 0);
            }
#pragma unroll
        for (int mt = 0; mt < 3; ++mt) aCur[mt] = aNxt[mt];
    }

    // epilogue: C/D layout col = lane&15 (t), row = (lane>>4)*4 + reg (o)
    // out1 = C(mm); out0 = C(x) - C(mm)
    int tw = t0 + ng * 32 + lr;
#pragma unroll
    for (int mt = 0; mt < 3; ++mt) {
        int o0 = mg * 48 + mt * 16 + lk * 4;
#pragma unroll
        for (int nt = 0; nt < 2; ++nt) {
#pragma unroll
            for (int r4 = 0; r4 < 4; ++r4) {
                size_t idx = xb + (size_t)(o0 + r4) * NC + tw + nt * 16;
                float vm = acc[mt][nt][1][r4];
                out1[idx] = vm;
                out0[idx] = acc[mt][nt][0][r4] - vm;
            }
        }
    }
}

extern "C" void kernel_launch(void* const* d_in, const int* in_sizes, int n_in,
                              void* d_out, int out_size, void* d_ws, size_t ws_size,
                              hipStream_t stream)
{
    const float* x      = (const float*)d_in[0];
    const float* conv_w = (const float*)d_in[1];
    const float* gate_w = (const float*)d_in[2];
    const float* gate_b = (const float*)d_in[3];

    float* out0 = (float*)d_out;
    float* out1 = out0 + (size_t)NB * NL * NC;

    unsigned short* awb    = (unsigned short*)d_ws;       // [96][288] bf16
    unsigned short* mstack = awb + (size_t)NL * KTOT;     // [3][96][96] bf16

    int prep_elems = NL * KTOT + 3 * 96 * 96;
    prep_kernel<<<dim3((prep_elems + 255) / 256), 256, 0, stream>>>(conv_w, awb, mstack);
    fused_kernel<<<dim3(NB, NC / TT), 256, 0, stream>>>(x, gate_w, gate_b, awb, mstack, out0, out1);
}